// Round 1
// 1012.380 us; speedup vs baseline: 1.0202x; 1.0202x over previous
//
#include <hip/hip_runtime.h>
#include <hip/hip_bf16.h>

// Shapes: B=4, S=4096, E=2048, NH=16, HD=128.  ST = B*S = 16384 rows.
// Layouts:
//   qbuf [16384][2048] bf16  (q projection)
//   Kt,Vt [64 bh][128 d][4096 s] bf16  (k/v projections, transposed per head)
//   kk,ktv [64 bh][128][128] f32 ; score_t [64 bh][128 e][128 d] bf16
//
// R4: qkv + FC GEMMs moved to the 256x256 8-phase schedule (HK-style):
//   BK=64, 8 waves (2Mx4N), 128KiB LDS double-buffer, raw s_barrier (NOT
//   __syncthreads -> no vmcnt(0) drain), counted s_waitcnt vmcnt(6) once per
//   K-tile, s_setprio(1) around each 16-MFMA cluster. LDS swizzle unchanged
//   from R3 (physical 16B chunk p of row r holds logical chunk p^(r&7),
//   applied on the global source address so global_load_lds stays linear).
//
// Stage-issue safety (region overwritten only after the barrier following its
// last read): per K-tile t the 4 phases read (A0+B0), (B1), (A1), (-) so
// B-halves are free after ph2 and A-halves after ph3. Issue map:
//   ph1: B1(t+1)  ph2: -   ph3: B0(t+2)   ph4: A0(t+2), A1(t+2), vmcnt(6)
// => at each ph4 vmcnt(6), exactly {B0,A0,A1}(t+2) (6 loads) remain in
// flight and all of tile t+1 has landed before any wave reads it.

typedef __attribute__((ext_vector_type(4))) float  f32x4;
typedef __attribute__((ext_vector_type(8))) short  s16x8;

__device__ __forceinline__ unsigned short f2bf(float f) {
  unsigned u = __float_as_uint(f);
  unsigned r = (u + 0x7FFFu + ((u >> 16) & 1u)) >> 16;   // RNE
  return (unsigned short)r;
}
__device__ __forceinline__ float bf2f(unsigned short u) {
  return __uint_as_float(((unsigned)u) << 16);
}

// async global->LDS, 16B per lane. LDS dest must be wave-uniform base + lane*16.
__device__ __forceinline__ void gld16(const void* g, void* l) {
  __builtin_amdgcn_global_load_lds(
      (const __attribute__((address_space(1))) unsigned int*)g,
      (__attribute__((address_space(3))) unsigned int*)l,
      16, 0, 0);
}

// ---------------------------------------------------------------- prep kernels
__global__ void cast_x_kernel(const float* __restrict__ x,
                              unsigned short* __restrict__ xb, long n) {
  long i = ((long)blockIdx.x * blockDim.x + threadIdx.x) * 4;
  if (i < n) {
    float4 v = *(const float4*)(x + i);
    ushort4 o;
    o.x = f2bf(v.x); o.y = f2bf(v.y); o.z = f2bf(v.z); o.w = f2bf(v.w);
    *(ushort4*)(xb + i) = o;
  }
}

// Wt[n][k] = W[k][n] as bf16. z picks Wq/Wk/Wv -> wqkv_t rows z*2048.., z=3 -> wfc_t.
__global__ void transw_kernel(const float* __restrict__ Wq, const float* __restrict__ Wk,
                              const float* __restrict__ Wv, const float* __restrict__ Wfc,
                              unsigned short* __restrict__ wqkv_t,
                              unsigned short* __restrict__ wfc_t) {
  __shared__ float tile[32][33];
  int z = blockIdx.z;
  const float* W = (z == 0) ? Wq : (z == 1) ? Wk : (z == 2) ? Wv : Wfc;
  unsigned short* dst = (z < 3) ? (wqkv_t + (size_t)z * 2048 * 2048) : wfc_t;
  int x0 = blockIdx.x * 32, y0 = blockIdx.y * 32;
  int tx = threadIdx.x & 31, ty = threadIdx.x >> 5;  // 256 thr: ty 0..7
#pragma unroll
  for (int r = 0; r < 4; ++r)
    tile[ty + r * 8][tx] = W[(size_t)(y0 + ty + r * 8) * 2048 + x0 + tx];
  __syncthreads();
#pragma unroll
  for (int r = 0; r < 4; ++r)
    dst[(size_t)(x0 + ty + r * 8) * 2048 + y0 + tx] = f2bf(tile[tx][ty + r * 8]);
}

__global__ void bias_kernel(const float* __restrict__ bq, const float* __restrict__ bk,
                            const float* __restrict__ bv, float* __restrict__ bqkv) {
  int i = blockIdx.x * 256 + threadIdx.x;  // 6144
  bqkv[i] = (i < 2048) ? bq[i] : (i < 4096) ? bk[i - 2048] : bv[i - 4096];
}

// --------------------------------------------------- 256x256 8-phase GEMM
#define BARRIER()  asm volatile("s_barrier" ::: "memory")
#define LGKM0()    asm volatile("s_waitcnt lgkmcnt(0)" ::: "memory")
#define VMCNT6()   asm volatile("s_waitcnt vmcnt(6)" ::: "memory")
#define VMCNT0()   asm volatile("s_waitcnt vmcnt(0)" ::: "memory")

// MODE 0: qkv fused epilogue (qbuf + transposed Kt/Vt, bias). A=xb, B=wqkv_t.
// MODE 1: fp32 out + bias (final FC). A=outat, B=wfc_t.
template <int MODE>
__global__ __launch_bounds__(512, 2)
void gemm256(const unsigned short* __restrict__ A, int lda,
             const unsigned short* __restrict__ Bw, int ldb,
             const float* __restrict__ bias,
             unsigned short* __restrict__ qbuf,
             unsigned short* __restrict__ Kt,
             unsigned short* __restrict__ Vt,
             float* __restrict__ outf, int K) {
  // LDS: A bufs at 0 / 32KB, B bufs at 64KB / 96KB. 128 KiB total.
  __shared__ __align__(16) unsigned short sb[65536];
  const int t = threadIdx.x;            // 0..511
  const int lane = t & 63;
  const int w = t >> 6;                 // 0..7
  const int wm = w >> 2, wn = w & 3;    // wave tile: rows wm*128, cols wn*64
  const int l15 = lane & 15, lq = lane >> 4;
  const int sx = l15 & 7;

  const unsigned short* Ab = A + (size_t)blockIdx.y * 256 * lda;
  const unsigned short* Bb = Bw + (size_t)blockIdx.x * 256 * ldb;

  // staging coords: thread t covers global row (t>>3), swizzled chunk (t&7)^(sr&7)
  const int sr = t >> 3;
  const int sc = ((t & 7) ^ (sr & 7)) * 8;

#define STAGE_A(kt, half, buf) do {                                             \
    const unsigned short* _g = Ab + (size_t)((half) * 128 + sr) * lda + (kt) * 64 + sc; \
    unsigned short* _l = sb + (buf) * 16384 + (half) * 8192 + t * 8;            \
    gld16(_g, _l);                                                              \
    gld16(_g + (size_t)64 * lda, _l + 4096);                                    \
  } while (0)
#define STAGE_B(kt, half, buf) do {                                             \
    const unsigned short* _g = Bb + (size_t)((half) * 128 + sr) * ldb + (kt) * 64 + sc; \
    unsigned short* _l = sb + 32768 + (buf) * 16384 + (half) * 8192 + t * 8;    \
    gld16(_g, _l);                                                              \
    gld16(_g + (size_t)64 * ldb, _l + 4096);                                    \
  } while (0)

#define LDA_FRAG(mq) do {                                                       \
    const unsigned short* _a = As_p + (wm * 128 + (mq) * 64 + l15) * 64;        \
    _Pragma("unroll") for (int i = 0; i < 4; ++i)                               \
      _Pragma("unroll") for (int ks = 0; ks < 2; ++ks)                          \
        af[i * 2 + ks] = *(const s16x8*)(_a + i * 1024 + ((ks * 4 + lq) ^ sx) * 8); \
  } while (0)
#define LDB_FRAG(dst, nq) do {                                                  \
    const unsigned short* _b = Bs_p + (wn * 64 + (nq) * 32 + l15) * 64;         \
    _Pragma("unroll") for (int jj = 0; jj < 2; ++jj)                            \
      _Pragma("unroll") for (int ks = 0; ks < 2; ++ks)                          \
        dst[jj * 2 + ks] = *(const s16x8*)(_b + jj * 1024 + ((ks * 4 + lq) ^ sx) * 8); \
  } while (0)
#define MMA_Q(mq, nq, bfr) do {                                                 \
    _Pragma("unroll") for (int i = 0; i < 4; ++i)                               \
      _Pragma("unroll") for (int jj = 0; jj < 2; ++jj) {                        \
        acc[(mq) * 4 + i][(nq) * 2 + jj] = __builtin_amdgcn_mfma_f32_16x16x32_bf16( \
            af[i * 2 + 0], bfr[jj * 2 + 0], acc[(mq) * 4 + i][(nq) * 2 + jj], 0, 0, 0); \
        acc[(mq) * 4 + i][(nq) * 2 + jj] = __builtin_amdgcn_mfma_f32_16x16x32_bf16( \
            af[i * 2 + 1], bfr[jj * 2 + 1], acc[(mq) * 4 + i][(nq) * 2 + jj], 0, 0, 0); \
      }                                                                         \
  } while (0)

// STG==2: steady state; STG==1: penultimate (stage B1(t+1) only, vmcnt(0));
// STG==0: last tile (no stage, no vmcnt). Requires nkt >= 3.
#define KTILE(tile, STG) do {                                                   \
    const int _p = (tile) & 1;                                                  \
    const unsigned short* As_p = sb + _p * 16384;                               \
    const unsigned short* Bs_p = sb + 32768 + _p * 16384;                       \
    s16x8 af[8], bf0[4], bf1[4];                                                \
    /* ph1: quadrant (0,0) */                                                   \
    LDA_FRAG(0);                                                                \
    LDB_FRAG(bf0, 0);                                                           \
    if ((STG) >= 1) STAGE_B((tile) + 1, 1, _p ^ 1);                             \
    BARRIER(); LGKM0();                                                         \
    __builtin_amdgcn_s_setprio(1); MMA_Q(0, 0, bf0); __builtin_amdgcn_s_setprio(0); \
    BARRIER();                                                                  \
    /* ph2: quadrant (0,1) */                                                   \
    LDB_FRAG(bf1, 1);                                                           \
    BARRIER(); LGKM0();                                                         \
    __builtin_amdgcn_s_setprio(1); MMA_Q(0, 1, bf1); __builtin_amdgcn_s_setprio(0); \
    BARRIER();                                                                  \
    /* ph3: quadrant (1,1) */                                                   \
    LDA_FRAG(1);                                                                \
    if ((STG) == 2) STAGE_B((tile) + 2, 0, _p);                                 \
    BARRIER(); LGKM0();                                                         \
    __builtin_amdgcn_s_setprio(1); MMA_Q(1, 1, bf1); __builtin_amdgcn_s_setprio(0); \
    BARRIER();                                                                  \
    /* ph4: quadrant (1,0) */                                                   \
    if ((STG) == 2) { STAGE_A((tile) + 2, 0, _p); STAGE_A((tile) + 2, 1, _p); VMCNT6(); } \
    else if ((STG) == 1) { VMCNT0(); }                                          \
    BARRIER();                                                                  \
    __builtin_amdgcn_s_setprio(1); MMA_Q(1, 0, bf0); __builtin_amdgcn_s_setprio(0); \
    BARRIER();                                                                  \
  } while (0)

  f32x4 acc[8][4] = {};
  const int nkt = K >> 6;

  // prologue: tile0 full into buf0, tile1 {A0,A1,B0} into buf1. 14 loads,
  // vmcnt(6) drains the oldest 8 (= tile0) before the first read.
  STAGE_A(0, 0, 0); STAGE_A(0, 1, 0);
  STAGE_B(0, 0, 0); STAGE_B(0, 1, 0);
  STAGE_A(1, 0, 1); STAGE_A(1, 1, 1);
  STAGE_B(1, 0, 1);
  VMCNT6();
  BARRIER();

  for (int tile = 0; tile < nkt - 2; ++tile) { KTILE(tile, 2); }
  KTILE(nkt - 2, 1);
  KTILE(nkt - 1, 0);

  // ---- epilogue ----
  const int colb = blockIdx.x * 256 + wn * 64 + l15;
  const long rowb = (long)blockIdx.y * 256 + wm * 128 + lq * 4;
  if (MODE == 0) {
    const int region = blockIdx.x >> 3;  // 0=q, 1=k, 2=v (N=6144, 8 blocks/region)
    if (region == 0) {
#pragma unroll
      for (int n = 0; n < 4; ++n) {
        int col = colb + n * 16;
        float bv = bias[col];
#pragma unroll
        for (int m = 0; m < 8; ++m) {
          long row = rowb + m * 16;
#pragma unroll
          for (int r = 0; r < 4; ++r)
            qbuf[(row + r) * 2048 + col] = f2bf(acc[m][n][r] + bv);
        }
      }
    } else {
      unsigned short* T = (region == 1) ? Kt : Vt;
#pragma unroll
      for (int n = 0; n < 4; ++n) {
        int col = colb + n * 16;
        float bv = bias[col];
        int cin = col & 2047;
        int d = cin & 127, h = cin >> 7;
#pragma unroll
        for (int m = 0; m < 8; ++m) {
          long row = rowb + m * 16;
          int b = (int)(row >> 12), s = (int)(row & 4095);
          ushort4 u;
          u.x = f2bf(acc[m][n][0] + bv);
          u.y = f2bf(acc[m][n][1] + bv);
          u.z = f2bf(acc[m][n][2] + bv);
          u.w = f2bf(acc[m][n][3] + bv);
          *(ushort4*)(T + (size_t)(b * 16 + h) * 524288 + (size_t)d * 4096 + s) = u;
        }
      }
    }
  } else {
#pragma unroll
    for (int n = 0; n < 4; ++n) {
      int col = colb + n * 16;
      float bv = bias[col];
#pragma unroll
      for (int m = 0; m < 8; ++m) {
        long row = rowb + m * 16;
#pragma unroll
        for (int r = 0; r < 4; ++r)
          outf[(row + r) * 2048 + col] = acc[m][n][r] + bv;
      }
    }
  }
#undef KTILE
#undef MMA_Q
#undef LDB_FRAG
#undef LDA_FRAG
#undef STAGE_B
#undef STAGE_A
}

// ---------------------------------------------------------------- K^T K, K^T V (MFMA)
// Per z: bh = z&63, op = (z>>6)&1 (0:kk, 1:ktv), split = z>>7 (K-split of 1024).
__global__ __launch_bounds__(256, 2)
void kk_gemm(const unsigned short* __restrict__ Kt,
             const unsigned short* __restrict__ Vt,
             float* __restrict__ kk, float* __restrict__ ktv) {
  __shared__ __align__(16) unsigned short As[128 * 64];
  __shared__ __align__(16) unsigned short Bs[128 * 64];
  const int t = threadIdx.x;
  const int lane = t & 63;
  const int w = t >> 6;
  const int wr = (w >> 1) * 64, wc = (w & 1) * 64;
  const int l15 = lane & 15, lq = lane >> 4;
  const int sxor = l15 & 7;
  const int bh = blockIdx.z & 63;
  const int op = (blockIdx.z >> 6) & 1;
  const int split = blockIdx.z >> 7;
  const unsigned short* Ab = Kt + (size_t)bh * 524288 + split * 1024;
  const unsigned short* Bb = (op ? Vt : Kt) + (size_t)bh * 524288 + split * 1024;
  float* C = (op ? ktv : kk) + (size_t)bh * 16384;

  f32x4 acc[4][4] = {};
  const int srow = t >> 3;
  const int scol = (((t & 7) ^ (srow & 7))) * 8;

  for (int kt = 0; kt < 16; ++kt) {
    const unsigned short* Ag = Ab + kt * 64 + (size_t)srow * 4096 + scol;
    const unsigned short* Bg = Bb + kt * 64 + (size_t)srow * 4096 + scol;
    __syncthreads();
#pragma unroll
    for (int i = 0; i < 4; ++i) {
      gld16(Ag + (size_t)(32 * i) * 4096, As + t * 8 + i * 2048);
      gld16(Bg + (size_t)(32 * i) * 4096, Bs + t * 8 + i * 2048);
    }
    __syncthreads();
#pragma unroll
    for (int ks = 0; ks < 2; ++ks) {
      const int ca = ((ks * 4 + lq) ^ sxor) * 8;
      s16x8 af[4], bf[4];
#pragma unroll
      for (int i = 0; i < 4; ++i) {
        af[i] = *(const s16x8*)(As + (wr + i * 16 + l15) * 64 + ca);
        bf[i] = *(const s16x8*)(Bs + (wc + i * 16 + l15) * 64 + ca);
      }
#pragma unroll
      for (int i = 0; i < 4; ++i)
#pragma unroll
        for (int j = 0; j < 4; ++j)
          acc[i][j] = __builtin_amdgcn_mfma_f32_16x16x32_bf16(af[i], bf[j], acc[i][j], 0, 0, 0);
    }
  }
  const int row0 = wr + lq * 4;
  const int col0 = wc + l15;
#pragma unroll
  for (int j = 0; j < 4; ++j)
#pragma unroll
    for (int i = 0; i < 4; ++i)
#pragma unroll
      for (int r = 0; r < 4; ++r)
        atomicAdd(&C[(row0 + i * 16 + r) * 128 + col0 + j * 16], acc[i][j][r]);
}

// ---------------------------------------------------------------- generic GEMM
// C[M,N] = A[M,K] * B^T[N,K] (+bias). Used for q@score (K=128, too shallow
// for the 8-phase pipeline).
template <bool OUT_BF16, bool HAS_BIAS>
__global__ __launch_bounds__(256, 2)
void gemm_bt(const unsigned short* __restrict__ A, int lda,
             const unsigned short* __restrict__ B, int ldb,
             const float* __restrict__ bias,
             void* __restrict__ C, int ldc, int K,
             long sAb, long sAh, long sBb, long sBh, long sCb, long sCh,
             int nhmod) {
  __shared__ __align__(16) unsigned short As[128 * 64];
  __shared__ __align__(16) unsigned short Bs[128 * 64];
  const int t = threadIdx.x;
  const int lane = t & 63;
  const int w = t >> 6;
  const int wr = (w >> 1) * 64, wc = (w & 1) * 64;
  const int l15 = lane & 15, lq = lane >> 4;
  const int sxor = l15 & 7;
  const int zb = blockIdx.z / nhmod, zh = blockIdx.z - zb * nhmod;
  const unsigned short* Ab = A + zb * sAb + zh * sAh + (size_t)blockIdx.y * 128 * lda;
  const unsigned short* Bb = B + zb * sBb + zh * sBh + (size_t)blockIdx.x * 128 * ldb;

  f32x4 acc[4][4] = {};
  const int nk = K >> 6;
  const int srow = t >> 3;
  const int scol = (((t & 7) ^ (srow & 7))) * 8;

  for (int kt = 0; kt < nk; ++kt) {
    const unsigned short* Ag = Ab + kt * 64 + (size_t)srow * lda + scol;
    const unsigned short* Bg = Bb + kt * 64 + (size_t)srow * ldb + scol;
    __syncthreads();
#pragma unroll
    for (int i = 0; i < 4; ++i) {
      gld16(Ag + (size_t)(32 * i) * lda, As + t * 8 + i * 2048);
      gld16(Bg + (size_t)(32 * i) * ldb, Bs + t * 8 + i * 2048);
    }
    __syncthreads();
#pragma unroll
    for (int ks = 0; ks < 2; ++ks) {
      const int ca = ((ks * 4 + lq) ^ sxor) * 8;
      s16x8 af[4], bf[4];
#pragma unroll
      for (int i = 0; i < 4; ++i) {
        af[i] = *(const s16x8*)(As + (wr + i * 16 + l15) * 64 + ca);
        bf[i] = *(const s16x8*)(Bs + (wc + i * 16 + l15) * 64 + ca);
      }
#pragma unroll
      for (int i = 0; i < 4; ++i)
#pragma unroll
        for (int j = 0; j < 4; ++j)
          acc[i][j] = __builtin_amdgcn_mfma_f32_16x16x32_bf16(af[i], bf[j], acc[i][j], 0, 0, 0);
    }
  }
  const long Cbase = zb * sCb + zh * sCh;
  const long row0 = (long)blockIdx.y * 128 + wr + lq * 4;
  const long col0 = (long)blockIdx.x * 128 + wc + l15;
#pragma unroll
  for (int j = 0; j < 4; ++j) {
    long col = col0 + j * 16;
    float bv = HAS_BIAS ? bias[col] : 0.0f;
#pragma unroll
    for (int i = 0; i < 4; ++i)
#pragma unroll
      for (int r = 0; r < 4; ++r) {
        float v = acc[i][j][r] + bv;
        long idx = Cbase + (row0 + i * 16 + r) * (long)ldc + col;
        if (OUT_BF16) ((unsigned short*)C)[idx] = f2bf(v);
        else          ((float*)C)[idx] = v;
      }
  }
}

// ------------------------------------------- inverse(alpha I + K^TK) @ K^TV, softmax
__global__ __launch_bounds__(256, 1)
void inv_softmax_kernel(const float* __restrict__ kk, const float* __restrict__ ktv,
                        const float* __restrict__ alphap,
                        unsigned short* __restrict__ score_t) {
  __shared__ __align__(16) float A[128 * 132];     // row stride 132 floats
  __shared__ __align__(16) float rowbuf[2][132];
  __shared__ __align__(16) float colbuf[2][132];
  const int bh = blockIdx.x, t = threadIdx.x;
  const float* kkb = kk + (size_t)bh * 16384;
  const float* tvb = ktv + (size_t)bh * 16384;
  const float al = alphap[0];

  for (int i = t; i < 16384; i += 256) {
    int r = i >> 7, c = i & 127;
    A[r * 132 + c] = kkb[i] + ((r == c) ? al : 0.0f);
  }
  __syncthreads();
  if (t < 128) { rowbuf[0][t] = A[t]; colbuf[0][t] = A[t * 132]; }
  __syncthreads();

  const int i2 = t >> 1, half = t & 1;
  const int jb = half * 64;
  for (int k = 0; k < 128; ++k) {
    const float* rb = rowbuf[k & 1];
    float piv = rb[k];
    float d = 1.0f / piv;
    float c = colbuf[k & 1][i2];
    bool isPivRow = (i2 == k);
    float cd = isPivRow ? 0.0f : c * d;
    float scale = isPivRow ? d : 1.0f;
    float* Arow = A + i2 * 132 + jb;
    const float* rbh = rb + jb;
#pragma unroll
    for (int jj = 0; jj < 16; ++jj) {
      float4 r4 = *(const float4*)(rbh + jj * 4);
      float4 v = *(float4*)(Arow + jj * 4);
      v.x = v.x * scale - cd * r4.x;
      v.y = v.y * scale - cd * r4.y;
      v.z = v.z * scale - cd * r4.z;
      v.w = v.w * scale - cd * r4.w;
      *(float4*)(Arow + jj * 4) = v;
    }
    if ((k >> 6) == half) {
      if (!isPivRow) A[i2 * 132 + k] = -c * d;
      else           A[k * 132 + k] = d;
    }
    __syncthreads();
    if (t < 128 && k < 127) {
      rowbuf[(k + 1) & 1][t] = A[(k + 1) * 132 + t];
      colbuf[(k + 1) & 1][t] = A[t * 132 + (k + 1)];
    }
    __syncthreads();
  }

  const int ty2 = t >> 4, tx2 = t & 15;
  float X[8][8] = {};
  for (int f = 0; f < 128; ++f) {
    float av[8];
#pragma unroll
    for (int i = 0; i < 8; ++i) av[i] = A[(ty2 * 8 + i) * 132 + f];
    float4 b0 = *(const float4*)(tvb + f * 128 + tx2 * 8);
    float4 b1 = *(const float4*)(tvb + f * 128 + tx2 * 8 + 4);
#pragma unroll
    for (int i = 0; i < 8; ++i) {
      X[i][0] = fmaf(av[i], b0.x, X[i][0]); X[i][1] = fmaf(av[i], b0.y, X[i][1]);
      X[i][2] = fmaf(av[i], b0.z, X[i][2]); X[i][3] = fmaf(av[i], b0.w, X[i][3]);
      X[i][4] = fmaf(av[i], b1.x, X[i][4]); X[i][5] = fmaf(av[i], b1.y, X[i][5]);
      X[i][6] = fmaf(av[i], b1.z, X[i][6]); X[i][7] = fmaf(av[i], b1.w, X[i][7]);
    }
  }
  __syncthreads();
#pragma unroll
  for (int i = 0; i < 8; ++i) {
    *(float4*)(A + (ty2 * 8 + i) * 132 + tx2 * 8)     = make_float4(X[i][0], X[i][1], X[i][2], X[i][3]);
    *(float4*)(A + (ty2 * 8 + i) * 132 + tx2 * 8 + 4) = make_float4(X[i][4], X[i][5], X[i][6], X[i][7]);
  }
  __syncthreads();
  {
    const int r = t >> 1;
    const float* row = A + r * 132 + (t & 1) * 64;
    float mx = -1e30f;
    for (int j = 0; j < 64; ++j) mx = fmaxf(mx, row[j]);
    mx = fmaxf(mx, __shfl_xor(mx, 1));
    float sum = 0.0f;
    for (int j = 0; j < 64; ++j) sum += __expf(row[j] - mx);
    sum += __shfl_xor(sum, 1);
    float inv = 1.0f / sum;
    unsigned short* outb = score_t + (size_t)bh * 16384 + r;
    const int e0 = (t & 1) * 64;
    for (int j = 0; j < 64; ++j)
      outb[(size_t)(e0 + j) * 128] = f2bf(__expf(row[j] - mx) * inv);
  }
}

// ---------------------------------------------------------------- launch
extern "C" void kernel_launch(void* const* d_in, const int* in_sizes, int n_in,
                              void* d_out, int out_size, void* d_ws, size_t ws_size,
                              hipStream_t stream) {
  const float* x     = (const float*)d_in[0];
  const float* alpha = (const float*)d_in[1];
  const float* Wq    = (const float*)d_in[2];
  const float* bq    = (const float*)d_in[3];
  const float* Wk    = (const float*)d_in[4];
  const float* bk    = (const float*)d_in[5];
  const float* Wv    = (const float*)d_in[6];
  const float* bv    = (const float*)d_in[7];
  const float* Wfc   = (const float*)d_in[8];
  const float* bfc   = (const float*)d_in[9];
  float* out = (float*)d_out;
  char* ws = (char*)d_ws;

  unsigned short* qbuf   = (unsigned short*)(ws);                    // 64MB
  unsigned short* Kt     = (unsigned short*)(ws + 67108864);         // 64MB
  unsigned short* Vt     = (unsigned short*)(ws + 134217728);        // 64MB
  unsigned short* xb     = (unsigned short*)(ws + 201326592);        // 64MB (dead after qkv)
  float* kkbuf           = (float*)(ws + 201326592);                 // alias xb: 4MB
  float* ktvbuf          = (float*)(ws + 201326592 + 4194304);       // 4MB
  unsigned short* score_t= (unsigned short*)(ws + 201326592 + 8388608); // 2MB
  unsigned short* outat  = Kt;                                       // alias Kt (dead after kk_gemm)
  unsigned short* wqkv_t = (unsigned short*)(ws + 268435456);        // 24MB
  unsigned short* wfc_t  = (unsigned short*)(ws + 293601280);        // 8MB
  float* bqkv            = (float*)(ws + 301989888);                 // 24KB

  transw_kernel<<<dim3(64, 64, 4), 256, 0, stream>>>(Wq, Wk, Wv, Wfc, wqkv_t, wfc_t);
  cast_x_kernel<<<32768, 256, 0, stream>>>(x, xb, 33554432L);
  bias_kernel<<<24, 256, 0, stream>>>(bq, bk, bv, bqkv);

  // fused QKV projection (256x256 8-phase); writes qbuf + transposed Kt/Vt
  gemm256<0><<<dim3(24, 64), 512, 0, stream>>>(
      xb, 2048, wqkv_t, 2048, bqkv, qbuf, Kt, Vt, nullptr, 2048);

  // K^TK, K^TV via MFMA, split-K=4, atomic fp32 accumulate
  hipMemsetAsync(kkbuf, 0, 8388608, stream);  // kk+ktv contiguous
  kk_gemm<<<dim3(1, 1, 512), 256, 0, stream>>>(Kt, Vt, kkbuf, ktvbuf);

  inv_softmax_kernel<<<64, 256, 0, stream>>>(kkbuf, ktvbuf, alpha, score_t);

  // out_attn[b,s,(h d)] = q[b,h] @ score[b,h]^T-layout : batched over z=bh, K=128
  gemm_bt<true, false><<<dim3(1, 32, 64), 256, 0, stream>>>(
      qbuf, 2048, score_t, 128, nullptr, outat, 2048, 128,
      8388608L, 128L,
      262144L, 16384L,
      8388608L, 128L,
      16);

  // final: out_attn @ Wfc + bfc -> fp32 d_out (256x256 8-phase)
  gemm256<1><<<dim3(8, 64), 512, 0, stream>>>(
      outat, 2048, wfc_t, 2048, bfc, nullptr, nullptr, nullptr, out, 2048);
}

// Round 2
// 990.145 us; speedup vs baseline: 1.0431x; 1.0225x over previous
//
#include <hip/hip_runtime.h>
#include <hip/hip_bf16.h>

// Shapes: B=4, S=4096, E=2048, NH=16, HD=128.  ST = B*S = 16384 rows.
// Layouts:
//   qbuf [16384][2048] bf16  (q projection)
//   Kt,Vt [64 bh][128 d][4096 s] bf16  (k/v projections, transposed per head)
//   kk,ktv [64 bh][128][128] f32 ; score_t [64 bh][128 e][128 d] bf16
//
// R5: 256x256 8-phase GEMM now uses ONE barrier per phase (was 2). R4's
// [all ds_read] -> bar -> [all MFMA] -> bar serialized LDS-read time and
// MFMA time (770 + 620 cyc per K-tile -> 45.8% MfmaUtil measured). With a
// single barrier between {frag reads + stage issue} and the MFMA cluster,
// waves skew within a phase so LDS reads overlap other waves' MFMAs.
//
// Region-exact stage safety (read map per K-tile t, buf p=t&1):
//   A rows: wm=0 reads rows 0-63 @ph1, 64-127 @ph3; wm=1 reads 128-191 @ph1,
//           192-255 @ph3  => A halves fully free only after ph3.
//   B rows: 32-row stripes alternate ph1(bf0)/ph2(bf1) per wn
//           => B halves fully free after ph2.
// Issue map (tile t+2 into buf p): ph3-top: B0,B1; ph4-top: A0,A1 + vmcnt(8).
// vmcnt(8) leaves exactly tile t+2's 8 loads in flight and drains tile t+1's
// loads (issued ph3/ph4 of tile t-1, 4-5 phases ~1000+ cyc earlier > HBM lat).

typedef __attribute__((ext_vector_type(4))) float  f32x4;
typedef __attribute__((ext_vector_type(8))) short  s16x8;

__device__ __forceinline__ unsigned short f2bf(float f) {
  unsigned u = __float_as_uint(f);
  unsigned r = (u + 0x7FFFu + ((u >> 16) & 1u)) >> 16;   // RNE
  return (unsigned short)r;
}
__device__ __forceinline__ float bf2f(unsigned short u) {
  return __uint_as_float(((unsigned)u) << 16);
}

// async global->LDS, 16B per lane. LDS dest must be wave-uniform base + lane*16.
__device__ __forceinline__ void gld16(const void* g, void* l) {
  __builtin_amdgcn_global_load_lds(
      (const __attribute__((address_space(1))) unsigned int*)g,
      (__attribute__((address_space(3))) unsigned int*)l,
      16, 0, 0);
}

// ---------------------------------------------------------------- prep kernels
__global__ void cast_x_kernel(const float* __restrict__ x,
                              unsigned short* __restrict__ xb, long n) {
  long i = ((long)blockIdx.x * blockDim.x + threadIdx.x) * 4;
  if (i < n) {
    float4 v = *(const float4*)(x + i);
    ushort4 o;
    o.x = f2bf(v.x); o.y = f2bf(v.y); o.z = f2bf(v.z); o.w = f2bf(v.w);
    *(ushort4*)(xb + i) = o;
  }
}

// Wt[n][k] = W[k][n] as bf16. z picks Wq/Wk/Wv -> wqkv_t rows z*2048.., z=3 -> wfc_t.
__global__ void transw_kernel(const float* __restrict__ Wq, const float* __restrict__ Wk,
                              const float* __restrict__ Wv, const float* __restrict__ Wfc,
                              unsigned short* __restrict__ wqkv_t,
                              unsigned short* __restrict__ wfc_t) {
  __shared__ float tile[32][33];
  int z = blockIdx.z;
  const float* W = (z == 0) ? Wq : (z == 1) ? Wk : (z == 2) ? Wv : Wfc;
  unsigned short* dst = (z < 3) ? (wqkv_t + (size_t)z * 2048 * 2048) : wfc_t;
  int x0 = blockIdx.x * 32, y0 = blockIdx.y * 32;
  int tx = threadIdx.x & 31, ty = threadIdx.x >> 5;  // 256 thr: ty 0..7
#pragma unroll
  for (int r = 0; r < 4; ++r)
    tile[ty + r * 8][tx] = W[(size_t)(y0 + ty + r * 8) * 2048 + x0 + tx];
  __syncthreads();
#pragma unroll
  for (int r = 0; r < 4; ++r)
    dst[(size_t)(x0 + ty + r * 8) * 2048 + y0 + tx] = f2bf(tile[tx][ty + r * 8]);
}

__global__ void bias_kernel(const float* __restrict__ bq, const float* __restrict__ bk,
                            const float* __restrict__ bv, float* __restrict__ bqkv) {
  int i = blockIdx.x * 256 + threadIdx.x;  // 6144
  bqkv[i] = (i < 2048) ? bq[i] : (i < 4096) ? bk[i - 2048] : bv[i - 4096];
}

// --------------------------------------------------- 256x256 8-phase GEMM
#define BARRIER()  asm volatile("s_barrier" ::: "memory")
#define VMCNT8()   asm volatile("s_waitcnt vmcnt(8)" ::: "memory")
#define VMCNT0()   asm volatile("s_waitcnt vmcnt(0)" ::: "memory")

// MODE 0: qkv fused epilogue (qbuf + transposed Kt/Vt, bias). A=xb, B=wqkv_t.
// MODE 1: fp32 out + bias (final FC). A=outat, B=wfc_t.
template <int MODE>
__global__ __launch_bounds__(512, 2)
void gemm256(const unsigned short* __restrict__ A, int lda,
             const unsigned short* __restrict__ Bw, int ldb,
             const float* __restrict__ bias,
             unsigned short* __restrict__ qbuf,
             unsigned short* __restrict__ Kt,
             unsigned short* __restrict__ Vt,
             float* __restrict__ outf, int K) {
  // LDS: A bufs at 0 / 32KB, B bufs at 64KB / 96KB. 128 KiB total.
  __shared__ __align__(16) unsigned short sb[65536];
  const int t = threadIdx.x;            // 0..511
  const int lane = t & 63;
  const int w = t >> 6;                 // 0..7
  const int wm = w >> 2, wn = w & 3;    // wave tile: rows wm*128, cols wn*64
  const int l15 = lane & 15, lq = lane >> 4;
  const int sx = l15 & 7;

  const unsigned short* Ab = A + (size_t)blockIdx.y * 256 * lda;
  const unsigned short* Bb = Bw + (size_t)blockIdx.x * 256 * ldb;

  // staging coords: thread t covers global row (t>>3), swizzled chunk (t&7)^(sr&7)
  const int sr = t >> 3;
  const int sc = ((t & 7) ^ (sr & 7)) * 8;

#define STAGE_A(kt, half, buf) do {                                             \
    const unsigned short* _g = Ab + (size_t)((half) * 128 + sr) * lda + (kt) * 64 + sc; \
    unsigned short* _l = sb + (buf) * 16384 + (half) * 8192 + t * 8;            \
    gld16(_g, _l);                                                              \
    gld16(_g + (size_t)64 * lda, _l + 4096);                                    \
  } while (0)
#define STAGE_B(kt, half, buf) do {                                             \
    const unsigned short* _g = Bb + (size_t)((half) * 128 + sr) * ldb + (kt) * 64 + sc; \
    unsigned short* _l = sb + 32768 + (buf) * 16384 + (half) * 8192 + t * 8;    \
    gld16(_g, _l);                                                              \
    gld16(_g + (size_t)64 * ldb, _l + 4096);                                    \
  } while (0)

#define LDA_FRAG(mq) do {                                                       \
    const unsigned short* _a = As_p + (wm * 128 + (mq) * 64 + l15) * 64;        \
    _Pragma("unroll") for (int i = 0; i < 4; ++i)                               \
      _Pragma("unroll") for (int ks = 0; ks < 2; ++ks)                          \
        af[i * 2 + ks] = *(const s16x8*)(_a + i * 1024 + ((ks * 4 + lq) ^ sx) * 8); \
  } while (0)
#define LDB_FRAG(dst, nq) do {                                                  \
    const unsigned short* _b = Bs_p + (wn * 64 + (nq) * 32 + l15) * 64;         \
    _Pragma("unroll") for (int jj = 0; jj < 2; ++jj)                            \
      _Pragma("unroll") for (int ks = 0; ks < 2; ++ks)                          \
        dst[jj * 2 + ks] = *(const s16x8*)(_b + jj * 1024 + ((ks * 4 + lq) ^ sx) * 8); \
  } while (0)
#define MMA_Q(mq, nq, bfr) do {                                                 \
    _Pragma("unroll") for (int i = 0; i < 4; ++i)                               \
      _Pragma("unroll") for (int jj = 0; jj < 2; ++jj) {                        \
        acc[(mq) * 4 + i][(nq) * 2 + jj] = __builtin_amdgcn_mfma_f32_16x16x32_bf16( \
            af[i * 2 + 0], bfr[jj * 2 + 0], acc[(mq) * 4 + i][(nq) * 2 + jj], 0, 0, 0); \
        acc[(mq) * 4 + i][(nq) * 2 + jj] = __builtin_amdgcn_mfma_f32_16x16x32_bf16( \
            af[i * 2 + 1], bfr[jj * 2 + 1], acc[(mq) * 4 + i][(nq) * 2 + jj], 0, 0, 0); \
      }                                                                         \
  } while (0)

// One barrier per phase: {frag ds_reads + stage issue} -> s_barrier -> MFMA.
// STG==2: steady state; STG==1: penultimate (no stage, vmcnt(0) at ph4);
// STG==0: last tile. Requires nkt >= 2.
#define KTILE(tile, STG) do {                                                   \
    const int _p = (tile) & 1;                                                  \
    const unsigned short* As_p = sb + _p * 16384;                               \
    const unsigned short* Bs_p = sb + 32768 + _p * 16384;                       \
    s16x8 af[8], bf0[4], bf1[4];                                                \
    /* ph1: quadrant (0,0) — reads A0,B0 frags */                               \
    LDA_FRAG(0);                                                                \
    LDB_FRAG(bf0, 0);                                                           \
    BARRIER();                                                                  \
    __builtin_amdgcn_s_setprio(1); MMA_Q(0, 0, bf0); __builtin_amdgcn_s_setprio(0); \
    /* ph2: quadrant (0,1) — reads B1 frags */                                  \
    LDB_FRAG(bf1, 1);                                                           \
    BARRIER();                                                                  \
    __builtin_amdgcn_s_setprio(1); MMA_Q(0, 1, bf1); __builtin_amdgcn_s_setprio(0); \
    /* ph3: quadrant (1,1) — reads A1 frags; B halves free after ph2 */         \
    LDA_FRAG(1);                                                                \
    if ((STG) == 2) { STAGE_B((tile) + 2, 0, _p); STAGE_B((tile) + 2, 1, _p); } \
    BARRIER();                                                                  \
    __builtin_amdgcn_s_setprio(1); MMA_Q(1, 1, bf1); __builtin_amdgcn_s_setprio(0); \
    /* ph4: quadrant (1,0) — A halves free after ph3; one vmem wait per tile */ \
    if ((STG) == 2) { STAGE_A((tile) + 2, 0, _p); STAGE_A((tile) + 2, 1, _p); VMCNT8(); } \
    else if ((STG) == 1) { VMCNT0(); }                                          \
    BARRIER();                                                                  \
    __builtin_amdgcn_s_setprio(1); MMA_Q(1, 0, bf0); __builtin_amdgcn_s_setprio(0); \
  } while (0)

  f32x4 acc[8][4] = {};
  const int nkt = K >> 6;

  // prologue: tile0 + tile1 fully staged (16 loads); vmcnt(8) drains tile0.
  STAGE_A(0, 0, 0); STAGE_A(0, 1, 0);
  STAGE_B(0, 0, 0); STAGE_B(0, 1, 0);
  STAGE_A(1, 0, 1); STAGE_A(1, 1, 1);
  STAGE_B(1, 0, 1); STAGE_B(1, 1, 1);
  VMCNT8();
  BARRIER();

  for (int tile = 0; tile < nkt - 2; ++tile) { KTILE(tile, 2); }
  KTILE(nkt - 2, 1);
  KTILE(nkt - 1, 0);

  // ---- epilogue ----
  const int colb = blockIdx.x * 256 + wn * 64 + l15;
  const long rowb = (long)blockIdx.y * 256 + wm * 128 + lq * 4;
  if (MODE == 0) {
    const int region = blockIdx.x >> 3;  // 0=q, 1=k, 2=v (N=6144, 8 blocks/region)
    if (region == 0) {
#pragma unroll
      for (int n = 0; n < 4; ++n) {
        int col = colb + n * 16;
        float bv = bias[col];
#pragma unroll
        for (int m = 0; m < 8; ++m) {
          long row = rowb + m * 16;
#pragma unroll
          for (int r = 0; r < 4; ++r)
            qbuf[(row + r) * 2048 + col] = f2bf(acc[m][n][r] + bv);
        }
      }
    } else {
      unsigned short* T = (region == 1) ? Kt : Vt;
#pragma unroll
      for (int n = 0; n < 4; ++n) {
        int col = colb + n * 16;
        float bv = bias[col];
        int cin = col & 2047;
        int d = cin & 127, h = cin >> 7;
#pragma unroll
        for (int m = 0; m < 8; ++m) {
          long row = rowb + m * 16;
          int b = (int)(row >> 12), s = (int)(row & 4095);
          ushort4 u;
          u.x = f2bf(acc[m][n][0] + bv);
          u.y = f2bf(acc[m][n][1] + bv);
          u.z = f2bf(acc[m][n][2] + bv);
          u.w = f2bf(acc[m][n][3] + bv);
          *(ushort4*)(T + (size_t)(b * 16 + h) * 524288 + (size_t)d * 4096 + s) = u;
        }
      }
    }
  } else {
#pragma unroll
    for (int n = 0; n < 4; ++n) {
      int col = colb + n * 16;
      float bv = bias[col];
#pragma unroll
      for (int m = 0; m < 8; ++m) {
        long row = rowb + m * 16;
#pragma unroll
        for (int r = 0; r < 4; ++r)
          outf[(row + r) * 2048 + col] = acc[m][n][r] + bv;
      }
    }
  }
#undef KTILE
#undef MMA_Q
#undef LDB_FRAG
#undef LDA_FRAG
#undef STAGE_B
#undef STAGE_A
}

// ---------------------------------------------------------------- K^T K, K^T V (MFMA)
// Per z: bh = z&63, op = (z>>6)&1 (0:kk, 1:ktv), split = z>>7 (K-split of 1024).
__global__ __launch_bounds__(256, 2)
void kk_gemm(const unsigned short* __restrict__ Kt,
             const unsigned short* __restrict__ Vt,
             float* __restrict__ kk, float* __restrict__ ktv) {
  __shared__ __align__(16) unsigned short As[128 * 64];
  __shared__ __align__(16) unsigned short Bs[128 * 64];
  const int t = threadIdx.x;
  const int lane = t & 63;
  const int w = t >> 6;
  const int wr = (w >> 1) * 64, wc = (w & 1) * 64;
  const int l15 = lane & 15, lq = lane >> 4;
  const int sxor = l15 & 7;
  const int bh = blockIdx.z & 63;
  const int op = (blockIdx.z >> 6) & 1;
  const int split = blockIdx.z >> 7;
  const unsigned short* Ab = Kt + (size_t)bh * 524288 + split * 1024;
  const unsigned short* Bb = (op ? Vt : Kt) + (size_t)bh * 524288 + split * 1024;
  float* C = (op ? ktv : kk) + (size_t)bh * 16384;

  f32x4 acc[4][4] = {};
  const int srow = t >> 3;
  const int scol = (((t & 7) ^ (srow & 7))) * 8;

  for (int kt = 0; kt < 16; ++kt) {
    const unsigned short* Ag = Ab + kt * 64 + (size_t)srow * 4096 + scol;
    const unsigned short* Bg = Bb + kt * 64 + (size_t)srow * 4096 + scol;
    __syncthreads();
#pragma unroll
    for (int i = 0; i < 4; ++i) {
      gld16(Ag + (size_t)(32 * i) * 4096, As + t * 8 + i * 2048);
      gld16(Bg + (size_t)(32 * i) * 4096, Bs + t * 8 + i * 2048);
    }
    __syncthreads();
#pragma unroll
    for (int ks = 0; ks < 2; ++ks) {
      const int ca = ((ks * 4 + lq) ^ sxor) * 8;
      s16x8 af[4], bf[4];
#pragma unroll
      for (int i = 0; i < 4; ++i) {
        af[i] = *(const s16x8*)(As + (wr + i * 16 + l15) * 64 + ca);
        bf[i] = *(const s16x8*)(Bs + (wc + i * 16 + l15) * 64 + ca);
      }
#pragma unroll
      for (int i = 0; i < 4; ++i)
#pragma unroll
        for (int j = 0; j < 4; ++j)
          acc[i][j] = __builtin_amdgcn_mfma_f32_16x16x32_bf16(af[i], bf[j], acc[i][j], 0, 0, 0);
    }
  }
  const int row0 = wr + lq * 4;
  const int col0 = wc + l15;
#pragma unroll
  for (int j = 0; j < 4; ++j)
#pragma unroll
    for (int i = 0; i < 4; ++i)
#pragma unroll
      for (int r = 0; r < 4; ++r)
        atomicAdd(&C[(row0 + i * 16 + r) * 128 + col0 + j * 16], acc[i][j][r]);
}

// ---------------------------------------------------------------- generic GEMM
// C[M,N] = A[M,K] * B^T[N,K] (+bias). Used for q@score (K=128, too shallow
// for the 8-phase pipeline).
template <bool OUT_BF16, bool HAS_BIAS>
__global__ __launch_bounds__(256, 2)
void gemm_bt(const unsigned short* __restrict__ A, int lda,
             const unsigned short* __restrict__ B, int ldb,
             const float* __restrict__ bias,
             void* __restrict__ C, int ldc, int K,
             long sAb, long sAh, long sBb, long sBh, long sCb, long sCh,
             int nhmod) {
  __shared__ __align__(16) unsigned short As[128 * 64];
  __shared__ __align__(16) unsigned short Bs[128 * 64];
  const int t = threadIdx.x;
  const int lane = t & 63;
  const int w = t >> 6;
  const int wr = (w >> 1) * 64, wc = (w & 1) * 64;
  const int l15 = lane & 15, lq = lane >> 4;
  const int sxor = l15 & 7;
  const int zb = blockIdx.z / nhmod, zh = blockIdx.z - zb * nhmod;
  const unsigned short* Ab = A + zb * sAb + zh * sAh + (size_t)blockIdx.y * 128 * lda;
  const unsigned short* Bb = B + zb * sBb + zh * sBh + (size_t)blockIdx.x * 128 * ldb;

  f32x4 acc[4][4] = {};
  const int nk = K >> 6;
  const int srow = t >> 3;
  const int scol = (((t & 7) ^ (srow & 7))) * 8;

  for (int kt = 0; kt < nk; ++kt) {
    const unsigned short* Ag = Ab + kt * 64 + (size_t)srow * lda + scol;
    const unsigned short* Bg = Bb + kt * 64 + (size_t)srow * ldb + scol;
    __syncthreads();
#pragma unroll
    for (int i = 0; i < 4; ++i) {
      gld16(Ag + (size_t)(32 * i) * lda, As + t * 8 + i * 2048);
      gld16(Bg + (size_t)(32 * i) * ldb, Bs + t * 8 + i * 2048);
    }
    __syncthreads();
#pragma unroll
    for (int ks = 0; ks < 2; ++ks) {
      const int ca = ((ks * 4 + lq) ^ sxor) * 8;
      s16x8 af[4], bf[4];
#pragma unroll
      for (int i = 0; i < 4; ++i) {
        af[i] = *(const s16x8*)(As + (wr + i * 16 + l15) * 64 + ca);
        bf[i] = *(const s16x8*)(Bs + (wc + i * 16 + l15) * 64 + ca);
      }
#pragma unroll
      for (int i = 0; i < 4; ++i)
#pragma unroll
        for (int j = 0; j < 4; ++j)
          acc[i][j] = __builtin_amdgcn_mfma_f32_16x16x32_bf16(af[i], bf[j], acc[i][j], 0, 0, 0);
    }
  }
  const long Cbase = zb * sCb + zh * sCh;
  const long row0 = (long)blockIdx.y * 128 + wr + lq * 4;
  const long col0 = (long)blockIdx.x * 128 + wc + l15;
#pragma unroll
  for (int j = 0; j < 4; ++j) {
    long col = col0 + j * 16;
    float bv = HAS_BIAS ? bias[col] : 0.0f;
#pragma unroll
    for (int i = 0; i < 4; ++i)
#pragma unroll
      for (int r = 0; r < 4; ++r) {
        float v = acc[i][j][r] + bv;
        long idx = Cbase + (row0 + i * 16 + r) * (long)ldc + col;
        if (OUT_BF16) ((unsigned short*)C)[idx] = f2bf(v);
        else          ((float*)C)[idx] = v;
      }
  }
}

// ------------------------------------------- inverse(alpha I + K^TK) @ K^TV, softmax
__global__ __launch_bounds__(256, 1)
void inv_softmax_kernel(const float* __restrict__ kk, const float* __restrict__ ktv,
                        const float* __restrict__ alphap,
                        unsigned short* __restrict__ score_t) {
  __shared__ __align__(16) float A[128 * 132];     // row stride 132 floats
  __shared__ __align__(16) float rowbuf[2][132];
  __shared__ __align__(16) float colbuf[2][132];
  const int bh = blockIdx.x, t = threadIdx.x;
  const float* kkb = kk + (size_t)bh * 16384;
  const float* tvb = ktv + (size_t)bh * 16384;
  const float al = alphap[0];

  for (int i = t; i < 16384; i += 256) {
    int r = i >> 7, c = i & 127;
    A[r * 132 + c] = kkb[i] + ((r == c) ? al : 0.0f);
  }
  __syncthreads();
  if (t < 128) { rowbuf[0][t] = A[t]; colbuf[0][t] = A[t * 132]; }
  __syncthreads();

  const int i2 = t >> 1, half = t & 1;
  const int jb = half * 64;
  for (int k = 0; k < 128; ++k) {
    const float* rb = rowbuf[k & 1];
    float piv = rb[k];
    float d = 1.0f / piv;
    float c = colbuf[k & 1][i2];
    bool isPivRow = (i2 == k);
    float cd = isPivRow ? 0.0f : c * d;
    float scale = isPivRow ? d : 1.0f;
    float* Arow = A + i2 * 132 + jb;
    const float* rbh = rb + jb;
#pragma unroll
    for (int jj = 0; jj < 16; ++jj) {
      float4 r4 = *(const float4*)(rbh + jj * 4);
      float4 v = *(float4*)(Arow + jj * 4);
      v.x = v.x * scale - cd * r4.x;
      v.y = v.y * scale - cd * r4.y;
      v.z = v.z * scale - cd * r4.z;
      v.w = v.w * scale - cd * r4.w;
      *(float4*)(Arow + jj * 4) = v;
    }
    if ((k >> 6) == half) {
      if (!isPivRow) A[i2 * 132 + k] = -c * d;
      else           A[k * 132 + k] = d;
    }
    __syncthreads();
    if (t < 128 && k < 127) {
      rowbuf[(k + 1) & 1][t] = A[(k + 1) * 132 + t];
      colbuf[(k + 1) & 1][t] = A[t * 132 + (k + 1)];
    }
    __syncthreads();
  }

  const int ty2 = t >> 4, tx2 = t & 15;
  float X[8][8] = {};
  for (int f = 0; f < 128; ++f) {
    float av[8];
#pragma unroll
    for (int i = 0; i < 8; ++i) av[i] = A[(ty2 * 8 + i) * 132 + f];
    float4 b0 = *(const float4*)(tvb + f * 128 + tx2 * 8);
    float4 b1 = *(const float4*)(tvb + f * 128 + tx2 * 8 + 4);
#pragma unroll
    for (int i = 0; i < 8; ++i) {
      X[i][0] = fmaf(av[i], b0.x, X[i][0]); X[i][1] = fmaf(av[i], b0.y, X[i][1]);
      X[i][2] = fmaf(av[i], b0.z, X[i][2]); X[i][3] = fmaf(av[i], b0.w, X[i][3]);
      X[i][4] = fmaf(av[i], b1.x, X[i][4]); X[i][5] = fmaf(av[i], b1.y, X[i][5]);
      X[i][6] = fmaf(av[i], b1.z, X[i][6]); X[i][7] = fmaf(av[i], b1.w, X[i][7]);
    }
  }
  __syncthreads();
#pragma unroll
  for (int i = 0; i < 8; ++i) {
    *(float4*)(A + (ty2 * 8 + i) * 132 + tx2 * 8)     = make_float4(X[i][0], X[i][1], X[i][2], X[i][3]);
    *(float4*)(A + (ty2 * 8 + i) * 132 + tx2 * 8 + 4) = make_float4(X[i][4], X[i][5], X[i][6], X[i][7]);
  }
  __syncthreads();
  {
    const int r = t >> 1;
    const float* row = A + r * 132 + (t & 1) * 64;
    float mx = -1e30f;
    for (int j = 0; j < 64; ++j) mx = fmaxf(mx, row[j]);
    mx = fmaxf(mx, __shfl_xor(mx, 1));
    float sum = 0.0f;
    for (int j = 0; j < 64; ++j) sum += __expf(row[j] - mx);
    sum += __shfl_xor(sum, 1);
    float inv = 1.0f / sum;
    unsigned short* outb = score_t + (size_t)bh * 16384 + r;
    const int e0 = (t & 1) * 64;
    for (int j = 0; j < 64; ++j)
      outb[(size_t)(e0 + j) * 128] = f2bf(__expf(row[j] - mx) * inv);
  }
}

// ---------------------------------------------------------------- launch
extern "C" void kernel_launch(void* const* d_in, const int* in_sizes, int n_in,
                              void* d_out, int out_size, void* d_ws, size_t ws_size,
                              hipStream_t stream) {
  const float* x     = (const float*)d_in[0];
  const float* alpha = (const float*)d_in[1];
  const float* Wq    = (const float*)d_in[2];
  const float* bq    = (const float*)d_in[3];
  const float* Wk    = (const float*)d_in[4];
  const float* bk    = (const float*)d_in[5];
  const float* Wv    = (const float*)d_in[6];
  const float* bv    = (const float*)d_in[7];
  const float* Wfc   = (const float*)d_in[8];
  const float* bfc   = (const float*)d_in[9];
  float* out = (float*)d_out;
  char* ws = (char*)d_ws;

  unsigned short* qbuf   = (unsigned short*)(ws);                    // 64MB
  unsigned short* Kt     = (unsigned short*)(ws + 67108864);         // 64MB
  unsigned short* Vt     = (unsigned short*)(ws + 134217728);        // 64MB
  unsigned short* xb     = (unsigned short*)(ws + 201326592);        // 64MB (dead after qkv)
  float* kkbuf           = (float*)(ws + 201326592);                 // alias xb: 4MB
  float* ktvbuf          = (float*)(ws + 201326592 + 4194304);       // 4MB
  unsigned short* score_t= (unsigned short*)(ws + 201326592 + 8388608); // 2MB
  unsigned short* outat  = Kt;                                       // alias Kt (dead after kk_gemm)
  unsigned short* wqkv_t = (unsigned short*)(ws + 268435456);        // 24MB
  unsigned short* wfc_t  = (unsigned short*)(ws + 293601280);        // 8MB
  float* bqkv            = (float*)(ws + 301989888);                 // 24KB

  transw_kernel<<<dim3(64, 64, 4), 256, 0, stream>>>(Wq, Wk, Wv, Wfc, wqkv_t, wfc_t);
  cast_x_kernel<<<32768, 256, 0, stream>>>(x, xb, 33554432L);
  bias_kernel<<<24, 256, 0, stream>>>(bq, bk, bv, bqkv);

  // fused QKV projection (256x256 8-phase, 1 barrier/phase); writes qbuf + Kt/Vt
  gemm256<0><<<dim3(24, 64), 512, 0, stream>>>(
      xb, 2048, wqkv_t, 2048, bqkv, qbuf, Kt, Vt, nullptr, 2048);

  // K^TK, K^TV via MFMA, split-K=4, atomic fp32 accumulate
  hipMemsetAsync(kkbuf, 0, 8388608, stream);  // kk+ktv contiguous
  kk_gemm<<<dim3(1, 1, 512), 256, 0, stream>>>(Kt, Vt, kkbuf, ktvbuf);

  inv_softmax_kernel<<<64, 256, 0, stream>>>(kkbuf, ktvbuf, alpha, score_t);

  // out_attn[b,s,(h d)] = q[b,h] @ score[b,h]^T-layout : batched over z=bh, K=128
  gemm_bt<true, false><<<dim3(1, 32, 64), 256, 0, stream>>>(
      qbuf, 2048, score_t, 128, nullptr, outat, 2048, 128,
      8388608L, 128L,
      262144L, 16384L,
      8388608L, 128L,
      16);

  // final: out_attn @ Wfc + bfc -> fp32 d_out (256x256 8-phase)
  gemm256<1><<<dim3(8, 64), 512, 0, stream>>>(
      outat, 2048, wfc_t, 2048, bfc, nullptr, nullptr, nullptr, out, 2048);
}